// Round 9
// baseline (214.509 us; speedup 1.0000x reference)
//
#include <hip/hip_runtime.h>
#include <hip/hip_fp16.h>
#include <math.h>

#define N_NODES 100000
#define N_EDGES 3200000
#define DIM 16
#define NSZ (N_NODES * DIM)

#define NPB 64          // nodes per bucket (bucket = col>>6, cl = col&63)
#define NBUCK_C 1563    // ceil(100000/64); last bucket has 32 valid nodes
#define NBLK 512        // sort partition blocks
#define EPB 6256        // edges per partition block; multiple of 4 for int4
#define CAP 2560        // aggregate LDS tile (mean 2048, +11 sigma)
#define PRK 5           // CAP/512 register-carried entries per thread

// packed entry: [63:47]=col(17) [46:30]=row(17) [29:0]=w bits>>2
typedef float nvec4 __attribute__((ext_vector_type(4)));

// ---- 1) prep: f32 state -> f16 (sin,cos) table; out1=x, out2=-x;
//         per-block bucket histogram -> tbl[bucket][blk] + totals ----
__global__ __launch_bounds__(512)
void prep(const float* __restrict__ state, const int* __restrict__ col,
          float* __restrict__ scp, float* __restrict__ out,
          unsigned* __restrict__ tbl, int* __restrict__ totals) {
    __shared__ int hcnt[NBUCK_C];               // 6.25 KB
    int t = threadIdx.x, blk = blockIdx.x;
    for (int j = t; j < NBUCK_C; j += 512) hcnt[j] = 0;
    int gid = blk * 512 + t, gsz = NBLK * 512;
    for (int i = gid; i < NSZ / 4; i += gsz) {
        nvec4 v = __builtin_nontemporal_load(&((const nvec4*)state)[i]);
        union { __half2 h[4]; nvec4 f; } u;
        u.h[0] = __floats2half2_rn(__sinf(v.x), __cosf(v.x));
        u.h[1] = __floats2half2_rn(__sinf(v.y), __cosf(v.y));
        u.h[2] = __floats2half2_rn(__sinf(v.z), __cosf(v.z));
        u.h[3] = __floats2half2_rn(__sinf(v.w), __cosf(v.w));
        ((nvec4*)scp)[i] = u.f;                 // reused by aggregate: keep cached
        __builtin_nontemporal_store(v, &((nvec4*)(out + 1 * (size_t)NSZ))[i]);
        nvec4 nv = {-v.x, -v.y, -v.z, -v.w};
        __builtin_nontemporal_store(nv, &((nvec4*)(out + 2 * (size_t)NSZ))[i]);
    }
    __syncthreads();
    int e0 = blk * EPB;
    int eN = e0 + EPB; if (eN > N_EDGES) eN = N_EDGES;
    int nch = (eN - e0) >> 2;
    const int4* c4p = (const int4*)(col + e0);
    for (int i = t; i < nch; i += 512) {
        int4 c = c4p[i];
        atomicAdd(&hcnt[c.x >> 6], 1);
        atomicAdd(&hcnt[c.y >> 6], 1);
        atomicAdd(&hcnt[c.z >> 6], 1);
        atomicAdd(&hcnt[c.w >> 6], 1);
    }
    __syncthreads();
    for (int j = t; j < NBUCK_C; j += 512) {
        int c = hcnt[j];
        tbl[(size_t)j * NBLK + blk] = (unsigned)c;
        if (c) atomicAdd(&totals[j], c);
    }
}

// ---- 2) exclusive scan of 1563 totals -> off[0..1563] ----
__global__ __launch_bounds__(1024)
void scan_off(const int* __restrict__ totals, int* __restrict__ off) {
    __shared__ int wsum[16];
    int t = threadIdx.x;
    int i0 = 2 * t, i1 = 2 * t + 1;
    int v0 = (i0 < NBUCK_C) ? totals[i0] : 0;
    int v1 = (i1 < NBUCK_C) ? totals[i1] : 0;
    int p = v0 + v1, ps = p;
    #pragma unroll
    for (int d = 1; d < 64; d <<= 1) {
        int u = __shfl_up(ps, d, 64);
        if ((t & 63) >= d) ps += u;
    }
    if ((t & 63) == 63) wsum[t >> 6] = ps;
    __syncthreads();
    int wid = t >> 6, wbase = 0;
    #pragma unroll
    for (int k = 0; k < 16; ++k) wbase += (k < wid) ? wsum[k] : 0;
    int ex = wbase + ps - p;
    if (i0 <= NBUCK_C) off[i0] = ex;
    if (i1 <= NBUCK_C) off[i1] = ex + v0;
}

// ---- 3) tbl counts -> global write bases, in place (shfl scan) ----
__global__ __launch_bounds__(512)
void base_scan(unsigned* __restrict__ tbl, const int* __restrict__ off) {
    __shared__ int wsum[8];
    int b = blockIdx.x, t = threadIdx.x;
    int v = (int)tbl[(size_t)b * NBLK + t];
    int ps = v;
    #pragma unroll
    for (int d = 1; d < 64; d <<= 1) {
        int u = __shfl_up(ps, d, 64);
        if ((t & 63) >= d) ps += u;
    }
    if ((t & 63) == 63) wsum[t >> 6] = ps;
    __syncthreads();
    int wid = t >> 6, wbase = 0;
    #pragma unroll
    for (int k = 0; k < 8; ++k) wbase += (k < wid) ? wsum[k] : 0;
    tbl[(size_t)b * NBLK + t] = (unsigned)(off[b] + wbase + ps - v);   // excl
}

// ---- 4) sort_write: per-block LDS radix to 1563 buckets, dense sweep.
//         diff[b] = gbase[b] - lstart[b] fuses the two sweep arrays. ----
__global__ __launch_bounds__(512)
void sort_write(const int* __restrict__ row, const int* __restrict__ col,
                const float* __restrict__ w, const unsigned* __restrict__ tbl,
                const int* __restrict__ off,
                unsigned long long* __restrict__ packed) {
    __shared__ unsigned long long sbuf[EPB];   // 50,048 B
    __shared__ int cur[NBUCK_C];               // counts -> scatter cursor
    __shared__ int diff[NBUCK_C];              // gbase -> gbase - lstart
    __shared__ int wsum[8];                    // total 62.6 KB
    int t = threadIdx.x, blk = blockIdx.x;
    int e0 = blk * EPB;
    int eN = e0 + EPB; if (eN > N_EDGES) eN = N_EDGES;
    int cnt = eN - e0;

    for (int j = t; j < NBUCK_C; j += 512) {   // bases + derived counts
        int b0 = (int)tbl[(size_t)j * NBLK + blk];
        int b1 = (blk == NBLK - 1) ? off[j + 1]
                                   : (int)tbl[(size_t)j * NBLK + blk + 1];
        diff[j] = b0;                          // gbase (temp)
        cur[j] = b1 - b0;                      // count
    }
    __syncthreads();
    {   // quad shfl exclusive scan over 2048 positions (NBUCK_C live)
        int base = 4 * t;
        int v0 = (base + 0 < NBUCK_C) ? cur[base + 0] : 0;
        int v1 = (base + 1 < NBUCK_C) ? cur[base + 1] : 0;
        int v2 = (base + 2 < NBUCK_C) ? cur[base + 2] : 0;
        int v3 = (base + 3 < NBUCK_C) ? cur[base + 3] : 0;
        int s = v0 + v1 + v2 + v3, ps = s;
        #pragma unroll
        for (int d = 1; d < 64; d <<= 1) {
            int u = __shfl_up(ps, d, 64);
            if ((t & 63) >= d) ps += u;
        }
        if ((t & 63) == 63) wsum[t >> 6] = ps;
        __syncthreads();
        int wid = t >> 6, wbase = 0;
        #pragma unroll
        for (int k = 0; k < 8; ++k) wbase += (k < wid) ? wsum[k] : 0;
        int e0x = wbase + ps - s;
        int e1x = e0x + v0, e2x = e1x + v1, e3x = e2x + v2;
        if (base + 0 < NBUCK_C) { diff[base + 0] -= e0x; cur[base + 0] = e0x; }
        if (base + 1 < NBUCK_C) { diff[base + 1] -= e1x; cur[base + 1] = e1x; }
        if (base + 2 < NBUCK_C) { diff[base + 2] -= e2x; cur[base + 2] = e2x; }
        if (base + 3 < NBUCK_C) { diff[base + 3] -= e3x; cur[base + 3] = e3x; }
    }
    __syncthreads();
    {   // single edge pass: int4 loads, LDS scatter by bucket
        int nch = cnt >> 2;
        const int4*   c4p = (const int4*)(col + e0);
        const int4*   r4p = (const int4*)(row + e0);
        const float4* w4p = (const float4*)(w + e0);
        for (int i = t; i < nch; i += 512) {
            int4 c = c4p[i]; int4 r = r4p[i]; float4 ww = w4p[i];
            int pos;
            pos = atomicAdd(&cur[c.x >> 6], 1);
            sbuf[pos] = ((unsigned long long)(unsigned)c.x << 47)
                      | ((unsigned long long)(unsigned)r.x << 30)
                      | (unsigned long long)(__float_as_uint(ww.x) >> 2);
            pos = atomicAdd(&cur[c.y >> 6], 1);
            sbuf[pos] = ((unsigned long long)(unsigned)c.y << 47)
                      | ((unsigned long long)(unsigned)r.y << 30)
                      | (unsigned long long)(__float_as_uint(ww.y) >> 2);
            pos = atomicAdd(&cur[c.z >> 6], 1);
            sbuf[pos] = ((unsigned long long)(unsigned)c.z << 47)
                      | ((unsigned long long)(unsigned)r.z << 30)
                      | (unsigned long long)(__float_as_uint(ww.z) >> 2);
            pos = atomicAdd(&cur[c.w >> 6], 1);
            sbuf[pos] = ((unsigned long long)(unsigned)c.w << 47)
                      | ((unsigned long long)(unsigned)r.w << 30)
                      | (unsigned long long)(__float_as_uint(ww.w) >> 2);
        }
    }
    __syncthreads();
    for (int i = t; i < cnt; i += 512) {       // dense sweep; bucket from entry
        unsigned long long pv = sbuf[i];
        int b = (int)(pv >> 53);               // col>>6
        __builtin_nontemporal_store(pv, &packed[diff[b] + i]);
    }
}

// S += w*sin_r, C += w*cos_r for 4 dims (lane q of a node group)
__device__ inline void acc_sc(float4& S, float4& C, unsigned long long p,
                              nvec4 h) {
    float we = __uint_as_float(((unsigned)p & 0x3FFFFFFFu) << 2);
    union { nvec4 f; __half2 h2[4]; } uu; uu.f = h;
    float2 f0 = __half22float2(uu.h2[0]);
    float2 f1 = __half22float2(uu.h2[1]);
    float2 f2 = __half22float2(uu.h2[2]);
    float2 f3 = __half22float2(uu.h2[3]);
    S.x += we * f0.x; C.x += we * f0.y;
    S.y += we * f1.x; C.y += we * f1.y;
    S.z += we * f2.x; C.z += we * f2.y;
    S.w += we * f3.x; C.w += we * f3.y;
}

// ---- 5) aggregate: one 64-node bucket per block, reads ONLY its own range.
//         512 thr = 64 nodes x 4 dim-lanes x 2 edge-subgroups; 4 blocks/CU. ----
__global__ __launch_bounds__(512, 8)
void aggregate(const float* __restrict__ state, const float* __restrict__ scp,
               const int* __restrict__ off,
               const unsigned long long* __restrict__ packed,
               float* __restrict__ out) {
    __shared__ unsigned long long sbuf[CAP];       // 20,480 B
    __shared__ nvec4 stage[3 * NPB * 4];           // 12,288 B epilogue staging
    __shared__ int s_cnt[NPB], s_start[NPB], s_cur[NPB];
    int b = blockIdx.x, t = threadIdx.x;
    int q = t & 3, sub = (t >> 2) & 1, g = t >> 3;   // node group 0..63
    int beg = off[b], end = off[b + 1];
    int n = b * NPB + g;
    bool valid = (n < N_NODES);
    float4 xx = valid ? ((const float4*)state)[n * 4 + q]
                      : make_float4(0.f, 0.f, 0.f, 0.f);
    float4 S = {0.f, 0.f, 0.f, 0.f}, C = {0.f, 0.f, 0.f, 0.f};
    const nvec4* scp4 = (const nvec4*)scp;

    for (int tbeg = beg; tbeg < end; tbeg += CAP) {
        int tend = tbeg + CAP; if (tend > end) tend = end;
        if (t < NPB) s_cnt[t] = 0;
        __syncthreads();

        // phase 1: coalesced read into registers; LDS cl-histogram
        unsigned long long pr[PRK];
        #pragma unroll
        for (int k = 0; k < PRK; ++k) {
            int e = tbeg + t + k * 512;
            if (e < tend) {
                pr[k] = __builtin_nontemporal_load(&packed[e]);
                atomicAdd(&s_cnt[(unsigned)(pr[k] >> 47) & 63u], 1);
            }
        }
        __syncthreads();

        // phase 2: 64-entry exclusive scan on first wave
        if (t < 64) {
            int v = s_cnt[t], ps = v;
            #pragma unroll
            for (int d = 1; d < 64; d <<= 1) {
                int uu = __shfl_up(ps, d, 64);
                if (t >= d) ps += uu;
            }
            s_start[t] = ps - v;
            s_cur[t] = ps - v;
        }
        __syncthreads();

        // phase 3: scatter from registers
        #pragma unroll
        for (int k = 0; k < PRK; ++k) {
            int e = tbeg + t + k * 512;
            if (e < tend) {
                int cl = (int)((pr[k] >> 47) & 63u);
                int pos = atomicAdd(&s_cur[cl], 1);
                sbuf[pos] = pr[k];
            }
        }
        __syncthreads();

        // phase 4: owner-computes; subgroup takes every 2nd edge, unroll-4
        {
            int es = s_start[g], ee = s_cur[g];
            int e = es + sub;
            for (; e + 6 < ee; e += 8) {
                unsigned long long p0 = sbuf[e];
                unsigned long long p1 = sbuf[e + 2];
                unsigned long long p2 = sbuf[e + 4];
                unsigned long long p3 = sbuf[e + 6];
                nvec4 h0 = scp4[(unsigned)((p0 >> 30) & 0x1FFFFu) * 4u + q];
                nvec4 h1 = scp4[(unsigned)((p1 >> 30) & 0x1FFFFu) * 4u + q];
                nvec4 h2 = scp4[(unsigned)((p2 >> 30) & 0x1FFFFu) * 4u + q];
                nvec4 h3 = scp4[(unsigned)((p3 >> 30) & 0x1FFFFu) * 4u + q];
                acc_sc(S, C, p0, h0);
                acc_sc(S, C, p1, h1);
                acc_sc(S, C, p2, h2);
                acc_sc(S, C, p3, h3);
            }
            for (; e < ee; e += 2) {
                unsigned long long p0 = sbuf[e];
                nvec4 h0 = scp4[(unsigned)((p0 >> 30) & 0x1FFFFu) * 4u + q];
                acc_sc(S, C, p0, h0);
            }
        }
        __syncthreads();
    }

    // merge 2 subgroups (lanes t, t^4 — same wave)
    S.x += __shfl_xor(S.x, 4, 64); S.y += __shfl_xor(S.y, 4, 64);
    S.z += __shfl_xor(S.z, 4, 64); S.w += __shfl_xor(S.w, 4, 64);
    C.x += __shfl_xor(C.x, 4, 64); C.y += __shfl_xor(C.y, 4, 64);
    C.z += __shfl_xor(C.z, 4, 64); C.w += __shfl_xor(C.w, 4, 64);

    if (sub == 0) {
        // agg = cos(x_c)*S - sin(x_c)*C  (f32 sincos of f32 state)
        float4 agg, th;
        float sx, cx;
        sx = __sinf(xx.x); cx = __cosf(xx.x); agg.x = cx * S.x - sx * C.x;
        sx = __sinf(xx.y); cx = __cosf(xx.y); agg.y = cx * S.y - sx * C.y;
        sx = __sinf(xx.z); cx = __cosf(xx.z); agg.z = cx * S.z - sx * C.z;
        sx = __sinf(xx.w); cx = __cosf(xx.w); agg.w = cx * S.w - sx * C.w;
        th.x = tanhf(agg.x); th.y = tanhf(agg.y);
        th.z = tanhf(agg.z); th.w = tanhf(agg.w);
        int slot = g * 4 + q;                         // 0..255
        stage[0 * 256 + slot] = (nvec4){th.x - xx.x, th.y - xx.y,
                                        th.z - xx.z, th.w - xx.w};
        stage[1 * 256 + slot] = (nvec4){agg.x, agg.y, agg.z, agg.w};
        stage[2 * 256 + slot] = (nvec4){th.x, th.y, th.z, th.w};
    }
    __syncthreads();
    int vn = N_NODES - b * NPB; if (vn > NPB) vn = NPB;
    int vslots = vn * 4;
    for (int i = t; i < 3 * 256; i += 512) {          // full-density burst write
        int a = i >> 8, slot = i & 255;
        if (slot < vslots) {
            nvec4 v = stage[i];
            size_t arr = (a == 0) ? 0 : ((a == 1) ? 3 : 4);
            __builtin_nontemporal_store(
                v, &((nvec4*)(out + arr * (size_t)NSZ))[b * 256 + slot]);
        }
    }
}

// ---- fallback (tiny ws): atomic path ----
__global__ __launch_bounds__(256)
void edge_kernel(const float* __restrict__ state, const int* __restrict__ row,
                 const int* __restrict__ col, const float* __restrict__ w,
                 float* __restrict__ agg) {
    int idx = blockIdx.x * blockDim.x + threadIdx.x;
    if (idx >= N_EDGES * 4) return;
    int e = idx >> 2, qq = idx & 3;
    int r = row[e], c = col[e];
    float we = w[e];
    const float4 xr = ((const float4*)state)[r * 4 + qq];
    const float4 xcv = ((const float4*)state)[c * 4 + qq];
    float* dst = agg + c * DIM + qq * 4;
    atomicAdd(dst + 0, sinf(xr.x - xcv.x) * we);
    atomicAdd(dst + 1, sinf(xr.y - xcv.y) * we);
    atomicAdd(dst + 2, sinf(xr.z - xcv.z) * we);
    atomicAdd(dst + 3, sinf(xr.w - xcv.w) * we);
}

__global__ __launch_bounds__(256)
void node_kernel(const float* __restrict__ state, const float* __restrict__ agg,
                 float* __restrict__ out) {
    int idx = blockIdx.x * blockDim.x + threadIdx.x;
    if (idx >= N_NODES * 4) return;
    float4 x = ((const float4*)state)[idx];
    float4 a = ((const float4*)agg)[idx];
    float4 tv = make_float4(tanhf(a.x), tanhf(a.y), tanhf(a.z), tanhf(a.w));
    ((float4*)(out + 0 * NSZ))[idx] = make_float4(tv.x - x.x, tv.y - x.y,
                                                  tv.z - x.z, tv.w - x.w);
    ((float4*)(out + 1 * NSZ))[idx] = x;
    ((float4*)(out + 2 * NSZ))[idx] = make_float4(-x.x, -x.y, -x.z, -x.w);
    ((float4*)(out + 4 * NSZ))[idx] = tv;
}

extern "C" void kernel_launch(void* const* d_in, const int* in_sizes, int n_in,
                              void* d_out, int out_size, void* d_ws, size_t ws_size,
                              hipStream_t stream) {
    const float* state = (const float*)d_in[0];
    const int*   row   = (const int*)d_in[1];
    const int*   col   = (const int*)d_in[2];
    const float* w     = (const float*)d_in[3];
    float* out = (float*)d_out;

    // ws: packed | scp (f16 sincos) | tbl | totals | off
    size_t packed_off = 0;
    size_t scp_off    = packed_off + (size_t)N_EDGES * 8;          // 25.6MB
    size_t tbl_off    = scp_off + (size_t)NSZ * 4;                 // +6.4MB
    size_t tot_off    = tbl_off + (size_t)NBUCK_C * NBLK * 4;      // +3.2MB
    size_t off_off    = tot_off + ((size_t)NBUCK_C * 4 + 15) / 16 * 16;
    size_t needed     = off_off + (size_t)(NBUCK_C + 2) * 4;

    if (ws_size >= needed) {
        unsigned long long* packed =
            (unsigned long long*)((char*)d_ws + packed_off);
        float* scp    = (float*)((char*)d_ws + scp_off);
        unsigned* tbl = (unsigned*)((char*)d_ws + tbl_off);
        int* totals   = (int*)((char*)d_ws + tot_off);
        int* off      = (int*)((char*)d_ws + off_off);

        (void)hipMemsetAsync(totals, 0, (size_t)NBUCK_C * sizeof(int), stream);
        prep<<<NBLK, 512, 0, stream>>>(state, col, scp, out, tbl, totals);
        scan_off<<<1, 1024, 0, stream>>>(totals, off);
        base_scan<<<NBUCK_C, 512, 0, stream>>>(tbl, off);
        sort_write<<<NBLK, 512, 0, stream>>>(row, col, w, tbl, off, packed);
        aggregate<<<NBUCK_C, 512, 0, stream>>>(state, scp, off, packed, out);
    } else {
        float* agg = out + 3 * NSZ;
        (void)hipMemsetAsync(agg, 0, NSZ * sizeof(float), stream);
        edge_kernel<<<(N_EDGES * 4 + 255) / 256, 256, 0, stream>>>(
            state, row, col, w, agg);
        node_kernel<<<(N_NODES * 4 + 255) / 256, 256, 0, stream>>>(
            state, agg, out);
    }
}

// Round 10
// 174.629 us; speedup vs baseline: 1.2284x; 1.2284x over previous
//
#include <hip/hip_runtime.h>
#include <hip/hip_fp16.h>
#include <math.h>

#define N_NODES 100000
#define N_EDGES 3200000
#define DIM 16
#define NSZ (N_NODES * DIM)

#define NPB 128         // nodes per bucket (bucket = col>>7, cl = col&127)
#define NBUCK 782       // ceil(100000/128); last bucket has 32 valid nodes
#define NBLK 512        // sort partition blocks
#define EPB 6256        // edges per partition block; multiple of 4 for int4
#define CAP 4864        // aggregate LDS tile (mean 4092, +12 sigma)
#define PRK 5           // ceil(CAP/1024) register-carried entries per thread

// packed entry: [63:47]=col(17) [46:30]=row(17) [29:0]=w bits>>2
typedef float nvec4 __attribute__((ext_vector_type(4)));

// ---- 1) prep: f32 state -> f16 table (3.2MB, L2-resident for gathers);
//         out1=x, out2=-x; per-block 782-histogram -> tbl + totals ----
__global__ __launch_bounds__(512)
void prep(const float* __restrict__ state, const int* __restrict__ col,
          __half* __restrict__ hs, float* __restrict__ out,
          unsigned* __restrict__ tbl, int* __restrict__ totals) {
    __shared__ int hcnt[NBUCK];                 // 3.1 KB
    int t = threadIdx.x, blk = blockIdx.x;
    for (int j = t; j < NBUCK; j += 512) hcnt[j] = 0;
    int gid = blk * 512 + t, gsz = NBLK * 512;
    for (int i = gid; i < NSZ / 4; i += gsz) {
        nvec4 v = __builtin_nontemporal_load(&((const nvec4*)state)[i]);
        union { __half2 h[2]; float2 f; } u;
        u.h[0] = __floats2half2_rn(v.x, v.y);
        u.h[1] = __floats2half2_rn(v.z, v.w);
        ((float2*)hs)[i] = u.f;                 // reused by aggregate: keep cached
        __builtin_nontemporal_store(v, &((nvec4*)(out + 1 * (size_t)NSZ))[i]);
        nvec4 nv = {-v.x, -v.y, -v.z, -v.w};
        __builtin_nontemporal_store(nv, &((nvec4*)(out + 2 * (size_t)NSZ))[i]);
    }
    __syncthreads();
    int e0 = blk * EPB;
    int eN = e0 + EPB; if (eN > N_EDGES) eN = N_EDGES;
    int nch = (eN - e0) >> 2;
    const int4* c4p = (const int4*)(col + e0);
    for (int i = t; i < nch; i += 512) {
        int4 c = c4p[i];
        atomicAdd(&hcnt[c.x >> 7], 1);
        atomicAdd(&hcnt[c.y >> 7], 1);
        atomicAdd(&hcnt[c.z >> 7], 1);
        atomicAdd(&hcnt[c.w >> 7], 1);
    }
    __syncthreads();
    for (int j = t; j < NBUCK; j += 512) {
        int c = hcnt[j];
        tbl[(size_t)j * NBLK + blk] = (unsigned)c;
        if (c) atomicAdd(&totals[j], c);
    }
}

// ---- 2) exclusive scan of 782 totals -> off[0..782] ----
__global__ __launch_bounds__(512)
void scan_off(const int* __restrict__ totals, int* __restrict__ off) {
    __shared__ int wsum[8];
    int t = threadIdx.x;
    int i0 = 2 * t, i1 = 2 * t + 1;
    int v0 = (i0 < NBUCK) ? totals[i0] : 0;
    int v1 = (i1 < NBUCK) ? totals[i1] : 0;
    int p = v0 + v1, ps = p;
    #pragma unroll
    for (int d = 1; d < 64; d <<= 1) {
        int u = __shfl_up(ps, d, 64);
        if ((t & 63) >= d) ps += u;
    }
    if ((t & 63) == 63) wsum[t >> 6] = ps;
    __syncthreads();
    int wid = t >> 6, wbase = 0;
    #pragma unroll
    for (int k = 0; k < 8; ++k) wbase += (k < wid) ? wsum[k] : 0;
    int ex = wbase + ps - p;
    if (i0 <= NBUCK) off[i0] = ex;
    if (i1 <= NBUCK) off[i1] = ex + v0;
}

// ---- 3) tbl counts -> global write bases, in place (shfl scan) ----
__global__ __launch_bounds__(512)
void base_scan(unsigned* __restrict__ tbl, const int* __restrict__ off) {
    __shared__ int wsum[8];
    int b = blockIdx.x, t = threadIdx.x;
    int v = (int)tbl[(size_t)b * NBLK + t];
    int ps = v;
    #pragma unroll
    for (int d = 1; d < 64; d <<= 1) {
        int u = __shfl_up(ps, d, 64);
        if ((t & 63) >= d) ps += u;
    }
    if ((t & 63) == 63) wsum[t >> 6] = ps;
    __syncthreads();
    int wid = t >> 6, wbase = 0;
    #pragma unroll
    for (int k = 0; k < 8; ++k) wbase += (k < wid) ? wsum[k] : 0;
    tbl[(size_t)b * NBLK + t] = (unsigned)(off[b] + wbase + ps - v);   // excl
}

// ---- 4) sort_write: per-block LDS radix to 782 buckets -> runs of ~8
//         entries (full 64B lines). diff[b] = gbase[b] - lstart[b]. ----
__global__ __launch_bounds__(512)
void sort_write(const int* __restrict__ row, const int* __restrict__ col,
                const float* __restrict__ w, const unsigned* __restrict__ tbl,
                const int* __restrict__ off,
                unsigned long long* __restrict__ packed) {
    __shared__ unsigned long long sbuf[EPB];   // 50,048 B
    __shared__ int cur[NBUCK];                 // counts -> scatter cursor
    __shared__ int diff[NBUCK];                // gbase -> gbase - lstart
    __shared__ int wsum[8];                    // total ~56.4 KB
    int t = threadIdx.x, blk = blockIdx.x;
    int e0 = blk * EPB;
    int eN = e0 + EPB; if (eN > N_EDGES) eN = N_EDGES;
    int cnt = eN - e0;

    for (int j = t; j < NBUCK; j += 512) {     // bases + derived counts
        int b0 = (int)tbl[(size_t)j * NBLK + blk];
        int b1 = (blk == NBLK - 1) ? off[j + 1]
                                   : (int)tbl[(size_t)j * NBLK + blk + 1];
        diff[j] = b0;                          // gbase (temp)
        cur[j] = b1 - b0;                      // count
    }
    __syncthreads();
    {   // pairwise shfl exclusive scan over 1024 positions (782 live)
        int i0 = 2 * t, i1 = 2 * t + 1;
        int v0 = (i0 < NBUCK) ? cur[i0] : 0;
        int v1 = (i1 < NBUCK) ? cur[i1] : 0;
        int p = v0 + v1, ps = p;
        #pragma unroll
        for (int d = 1; d < 64; d <<= 1) {
            int u = __shfl_up(ps, d, 64);
            if ((t & 63) >= d) ps += u;
        }
        if ((t & 63) == 63) wsum[t >> 6] = ps;
        __syncthreads();
        int wid = t >> 6, wbase = 0;
        #pragma unroll
        for (int k = 0; k < 8; ++k) wbase += (k < wid) ? wsum[k] : 0;
        int ex = wbase + ps - p;
        if (i0 < NBUCK) { diff[i0] -= ex;      cur[i0] = ex; }
        if (i1 < NBUCK) { diff[i1] -= ex + v0; cur[i1] = ex + v0; }
    }
    __syncthreads();
    {   // single edge pass: int4 loads, LDS scatter by bucket
        int nch = cnt >> 2;
        const int4*   c4p = (const int4*)(col + e0);
        const int4*   r4p = (const int4*)(row + e0);
        const float4* w4p = (const float4*)(w + e0);
        for (int i = t; i < nch; i += 512) {
            int4 c = c4p[i]; int4 r = r4p[i]; float4 ww = w4p[i];
            int pos;
            pos = atomicAdd(&cur[c.x >> 7], 1);
            sbuf[pos] = ((unsigned long long)(unsigned)c.x << 47)
                      | ((unsigned long long)(unsigned)r.x << 30)
                      | (unsigned long long)(__float_as_uint(ww.x) >> 2);
            pos = atomicAdd(&cur[c.y >> 7], 1);
            sbuf[pos] = ((unsigned long long)(unsigned)c.y << 47)
                      | ((unsigned long long)(unsigned)r.y << 30)
                      | (unsigned long long)(__float_as_uint(ww.y) >> 2);
            pos = atomicAdd(&cur[c.z >> 7], 1);
            sbuf[pos] = ((unsigned long long)(unsigned)c.z << 47)
                      | ((unsigned long long)(unsigned)r.z << 30)
                      | (unsigned long long)(__float_as_uint(ww.z) >> 2);
            pos = atomicAdd(&cur[c.w >> 7], 1);
            sbuf[pos] = ((unsigned long long)(unsigned)c.w << 47)
                      | ((unsigned long long)(unsigned)r.w << 30)
                      | (unsigned long long)(__float_as_uint(ww.w) >> 2);
        }
    }
    __syncthreads();
    for (int i = t; i < cnt; i += 512) {       // dense sweep; bucket from entry
        unsigned long long pv = sbuf[i];
        int b = (int)(pv >> 54);               // col>>7
        __builtin_nontemporal_store(pv, &packed[diff[b] + i]);
    }
}

// ---- 5) aggregate: 1024 thr = 128 nodes x 4 dim-lanes x 2 edge-subgroups.
//         f16 state gather (32 B/edge, table L2-resident); sin in VALU
//         (hidden under gather latency). No LDS stage: sub0 lanes cover
//         full 64B lines directly. 2 blocks/CU -> 32 waves. ----
__global__ __launch_bounds__(1024, 8)
void aggregate(const float* __restrict__ state, const __half2* __restrict__ hs2,
               const int* __restrict__ off,
               const unsigned long long* __restrict__ packed,
               float* __restrict__ out) {
    __shared__ unsigned long long sbuf[CAP];       // 38,912 B
    __shared__ int s_cnt[NPB], s_start[NPB], s_cur[NPB];
    __shared__ int s_wsum;
    int b = blockIdx.x, t = threadIdx.x;
    int q = t & 3, sub = (t >> 2) & 1, g = t >> 3;   // node group 0..127
    int beg = off[b], end = off[b + 1];
    int n = b * NPB + g;
    bool valid = (n < N_NODES);
    float4 xx = valid ? ((const float4*)state)[n * 4 + q]
                      : make_float4(0.f, 0.f, 0.f, 0.f);
    float4 acc = {0.f, 0.f, 0.f, 0.f};
    const uint2* hsu = (const uint2*)hs2;            // 8 B = 4 halfs per lane

    for (int tbeg = beg; tbeg < end; tbeg += CAP) {
        int tend = tbeg + CAP; if (tend > end) tend = end;
        if (t < NPB) s_cnt[t] = 0;
        __syncthreads();

        // phase 1: coalesced read into registers; LDS cl-histogram
        unsigned long long pr[PRK];
        #pragma unroll
        for (int k = 0; k < PRK; ++k) {
            int e = tbeg + t + k * 1024;
            if (e < tend) {
                pr[k] = __builtin_nontemporal_load(&packed[e]);
                atomicAdd(&s_cnt[(unsigned)(pr[k] >> 47) & 127u], 1);
            }
        }
        __syncthreads();

        // phase 2: 128-entry exclusive scan on waves 0,1
        {
            int v = 0, ps = 0;
            if (t < NPB) {
                v = s_cnt[t]; ps = v;
                #pragma unroll
                for (int d = 1; d < 64; d <<= 1) {
                    int u = __shfl_up(ps, d, 64);
                    if ((t & 63) >= d) ps += u;
                }
            }
            if (t == 63) s_wsum = ps;
            __syncthreads();
            if (t < NPB) {
                int ex = ps - v + ((t >= 64) ? s_wsum : 0);
                s_start[t] = ex;
                s_cur[t] = ex;
            }
        }
        __syncthreads();

        // phase 3: scatter from registers
        #pragma unroll
        for (int k = 0; k < PRK; ++k) {
            int e = tbeg + t + k * 1024;
            if (e < tend) {
                int cl = (int)((pr[k] >> 47) & 127u);
                int pos = atomicAdd(&s_cur[cl], 1);
                sbuf[pos] = pr[k];
            }
        }
        __syncthreads();

        // phase 4: owner-computes; subgroup takes every 2nd edge, unroll-4
        {
            int es = s_start[g], ee = s_cur[g];
            int e = es + sub;
            for (; e + 6 < ee; e += 8) {
                unsigned long long p0 = sbuf[e];
                unsigned long long p1 = sbuf[e + 2];
                unsigned long long p2 = sbuf[e + 4];
                unsigned long long p3 = sbuf[e + 6];
                uint2 h0 = hsu[(unsigned)((p0 >> 30) & 0x1FFFFu) * 4u + q];
                uint2 h1 = hsu[(unsigned)((p1 >> 30) & 0x1FFFFu) * 4u + q];
                uint2 h2 = hsu[(unsigned)((p2 >> 30) & 0x1FFFFu) * 4u + q];
                uint2 h3 = hsu[(unsigned)((p3 >> 30) & 0x1FFFFu) * 4u + q];
                #pragma unroll
                for (int j = 0; j < 4; ++j) {
                    unsigned long long p = (j == 0) ? p0 : (j == 1) ? p1
                                         : (j == 2) ? p2 : p3;
                    uint2 hb = (j == 0) ? h0 : (j == 1) ? h1
                             : (j == 2) ? h2 : h3;
                    float we = __uint_as_float(((unsigned)p & 0x3FFFFFFFu) << 2);
                    float2 lo = __half22float2(*(const __half2*)&hb.x);
                    float2 hi = __half22float2(*(const __half2*)&hb.y);
                    acc.x += __sinf(lo.x - xx.x) * we;
                    acc.y += __sinf(lo.y - xx.y) * we;
                    acc.z += __sinf(hi.x - xx.z) * we;
                    acc.w += __sinf(hi.y - xx.w) * we;
                }
            }
            for (; e < ee; e += 2) {
                unsigned long long p = sbuf[e];
                uint2 hb = hsu[(unsigned)((p >> 30) & 0x1FFFFu) * 4u + q];
                float we = __uint_as_float(((unsigned)p & 0x3FFFFFFFu) << 2);
                float2 lo = __half22float2(*(const __half2*)&hb.x);
                float2 hi = __half22float2(*(const __half2*)&hb.y);
                acc.x += __sinf(lo.x - xx.x) * we;
                acc.y += __sinf(lo.y - xx.y) * we;
                acc.z += __sinf(hi.x - xx.z) * we;
                acc.w += __sinf(hi.y - xx.w) * we;
            }
        }
        __syncthreads();
    }

    // merge 2 subgroups (lanes t, t^4 — same wave, same g and q)
    acc.x += __shfl_xor(acc.x, 4, 64); acc.y += __shfl_xor(acc.y, 4, 64);
    acc.z += __shfl_xor(acc.z, 4, 64); acc.w += __shfl_xor(acc.w, 4, 64);

    if (valid && sub == 0) {
        // sub0 lanes (t in {0-3,8-11,...}) write consecutive 16B chunks:
        // each 64B line fully covered by one wave instruction -> no RMW.
        float4 th = make_float4(tanhf(acc.x), tanhf(acc.y),
                                tanhf(acc.z), tanhf(acc.w));
        int gdx = n * 4 + q;
        nvec4 v0 = {th.x - xx.x, th.y - xx.y, th.z - xx.z, th.w - xx.w};
        nvec4 v3 = {acc.x, acc.y, acc.z, acc.w};
        nvec4 v4 = {th.x, th.y, th.z, th.w};
        __builtin_nontemporal_store(v0, &((nvec4*)(out + 0 * (size_t)NSZ))[gdx]);
        __builtin_nontemporal_store(v3, &((nvec4*)(out + 3 * (size_t)NSZ))[gdx]);
        __builtin_nontemporal_store(v4, &((nvec4*)(out + 4 * (size_t)NSZ))[gdx]);
    }
}

// ---- fallback (tiny ws): atomic path ----
__global__ __launch_bounds__(256)
void edge_kernel(const float* __restrict__ state, const int* __restrict__ row,
                 const int* __restrict__ col, const float* __restrict__ w,
                 float* __restrict__ agg) {
    int idx = blockIdx.x * blockDim.x + threadIdx.x;
    if (idx >= N_EDGES * 4) return;
    int e = idx >> 2, qq = idx & 3;
    int r = row[e], c = col[e];
    float we = w[e];
    const float4 xr = ((const float4*)state)[r * 4 + qq];
    const float4 xcv = ((const float4*)state)[c * 4 + qq];
    float* dst = agg + c * DIM + qq * 4;
    atomicAdd(dst + 0, sinf(xr.x - xcv.x) * we);
    atomicAdd(dst + 1, sinf(xr.y - xcv.y) * we);
    atomicAdd(dst + 2, sinf(xr.z - xcv.z) * we);
    atomicAdd(dst + 3, sinf(xr.w - xcv.w) * we);
}

__global__ __launch_bounds__(256)
void node_kernel(const float* __restrict__ state, const float* __restrict__ agg,
                 float* __restrict__ out) {
    int idx = blockIdx.x * blockDim.x + threadIdx.x;
    if (idx >= N_NODES * 4) return;
    float4 x = ((const float4*)state)[idx];
    float4 a = ((const float4*)agg)[idx];
    float4 tv = make_float4(tanhf(a.x), tanhf(a.y), tanhf(a.z), tanhf(a.w));
    ((float4*)(out + 0 * NSZ))[idx] = make_float4(tv.x - x.x, tv.y - x.y,
                                                  tv.z - x.z, tv.w - x.w);
    ((float4*)(out + 1 * NSZ))[idx] = x;
    ((float4*)(out + 2 * NSZ))[idx] = make_float4(-x.x, -x.y, -x.z, -x.w);
    ((float4*)(out + 4 * NSZ))[idx] = tv;
}

extern "C" void kernel_launch(void* const* d_in, const int* in_sizes, int n_in,
                              void* d_out, int out_size, void* d_ws, size_t ws_size,
                              hipStream_t stream) {
    const float* state = (const float*)d_in[0];
    const int*   row   = (const int*)d_in[1];
    const int*   col   = (const int*)d_in[2];
    const float* w     = (const float*)d_in[3];
    float* out = (float*)d_out;

    // ws: packed | hs (f16 state) | tbl | totals | off
    size_t packed_off = 0;
    size_t hs_off     = packed_off + (size_t)N_EDGES * 8;          // 25.6MB
    size_t tbl_off    = hs_off + (size_t)NSZ * 2;                  // +3.2MB
    size_t tot_off    = tbl_off + (size_t)NBUCK * NBLK * 4;        // +1.6MB
    size_t off_off    = tot_off + ((size_t)NBUCK * 4 + 15) / 16 * 16;
    size_t needed     = off_off + (size_t)(NBUCK + 2) * 4;

    if (ws_size >= needed) {
        unsigned long long* packed =
            (unsigned long long*)((char*)d_ws + packed_off);
        __half* hs    = (__half*)((char*)d_ws + hs_off);
        unsigned* tbl = (unsigned*)((char*)d_ws + tbl_off);
        int* totals   = (int*)((char*)d_ws + tot_off);
        int* off      = (int*)((char*)d_ws + off_off);

        (void)hipMemsetAsync(totals, 0, (size_t)NBUCK * sizeof(int), stream);
        prep<<<NBLK, 512, 0, stream>>>(state, col, hs, out, tbl, totals);
        scan_off<<<1, 512, 0, stream>>>(totals, off);
        base_scan<<<NBUCK, 512, 0, stream>>>(tbl, off);
        sort_write<<<NBLK, 512, 0, stream>>>(row, col, w, tbl, off, packed);
        aggregate<<<NBUCK, 1024, 0, stream>>>(
            state, (const __half2*)hs, off, packed, out);
    } else {
        float* agg = out + 3 * NSZ;
        (void)hipMemsetAsync(agg, 0, NSZ * sizeof(float), stream);
        edge_kernel<<<(N_EDGES * 4 + 255) / 256, 256, 0, stream>>>(
            state, row, col, w, agg);
        node_kernel<<<(N_NODES * 4 + 255) / 256, 256, 0, stream>>>(
            state, agg, out);
    }
}